// Round 8
// baseline (458.707 us; speedup 1.0000x reference)
//
#include <hip/hip_runtime.h>

// dims
#define L_   384
#define D_   512
#define C_   256
#define H_   4
#define RR_  256
#define M1_  98304   // R*L
#define LL2_ 147456  // L*L
#define NPAIR_BLOCKS 18480  // 73920 pairs / 4 waves per block

typedef __bf16 bf16x8 __attribute__((ext_vector_type(8)));
typedef float f32x4 __attribute__((ext_vector_type(4)));

__device__ __forceinline__ unsigned short f2bf_bits(float f) {
  union { float f; unsigned u; } v; v.f = f;
  return (unsigned short)((v.u + 0x7fffu + ((v.u >> 16) & 1u)) >> 16);
}
__device__ __forceinline__ __bf16 f2bf(float f) {
  union { unsigned short s; __bf16 b; } o; o.s = f2bf_bits(f);
  return o.b;
}

__device__ __forceinline__ float wave_sum(float v) {
#pragma unroll
  for (int o = 32; o > 0; o >>= 1) v += __shfl_xor(v, o);
  return v;
}
__device__ __forceinline__ float wave_max(float v) {
#pragma unroll
  for (int o = 32; o > 0; o >>= 1) v = fmaxf(v, __shfl_xor(v, o));
  return v;
}

// ------ K3: pair symmetrize + LN + per-head logits (+mask) ------
__global__ __launch_bounds__(256) void pair_logits_kernel(
    const float* __restrict__ pf, const int* __restrict__ mask,
    const float* __restrict__ g, const float* __restrict__ b,
    const float* __restrict__ Wp, float* __restrict__ logits) {
  unsigned wid = blockIdx.x * 4 + (threadIdx.x >> 6);  // 0..73919
  int lane = threadIdx.x & 63;
  unsigned a = wid / 385u;
  unsigned c = wid - a * 385u;
  int i, j;
  if (c < 384u - a) { i = a; j = a + c; }
  else { i = 383 - a; j = i + (c - (384 - a)); }

  int c0 = lane * 4;
  float4 p1 = *(const float4*)(pf + ((size_t)i * L_ + j) * C_ + c0);
  float4 p2 = *(const float4*)(pf + ((size_t)j * L_ + i) * C_ + c0);
  float4 v;
  v.x = 0.5f * (p1.x + p2.x); v.y = 0.5f * (p1.y + p2.y);
  v.z = 0.5f * (p1.z + p2.z); v.w = 0.5f * (p1.w + p2.w);
  float s1 = v.x + v.y + v.z + v.w;
  float s2 = v.x * v.x + v.y * v.y + v.z * v.z + v.w * v.w;
#pragma unroll
  for (int o = 32; o > 0; o >>= 1) {
    s1 += __shfl_xor(s1, o);
    s2 += __shfl_xor(s2, o);
  }
  float mu = s1 * (1.0f / C_);
  float var = s2 * (1.0f / C_) - mu * mu;
  float rs = rsqrtf(var + 1e-5f);
  float4 gv = *(const float4*)(g + c0);
  float4 bv = *(const float4*)(b + c0);
  float y0 = (v.x - mu) * rs * gv.x + bv.x;
  float y1 = (v.y - mu) * rs * gv.y + bv.y;
  float y2 = (v.z - mu) * rs * gv.z + bv.z;
  float y3 = (v.w - mu) * rs * gv.w + bv.w;
  const float4* wp = (const float4*)Wp;  // [256][4]
  float4 w0 = wp[c0], w1 = wp[c0 + 1], w2 = wp[c0 + 2], w3 = wp[c0 + 3];
  float4 t;
  t.x = y0 * w0.x + y1 * w1.x + y2 * w2.x + y3 * w3.x;
  t.y = y0 * w0.y + y1 * w1.y + y2 * w2.y + y3 * w3.y;
  t.z = y0 * w0.z + y1 * w1.z + y2 * w2.z + y3 * w3.z;
  t.w = y0 * w0.w + y1 * w1.w + y2 * w2.w + y3 * w3.w;
#pragma unroll
  for (int o = 32; o > 0; o >>= 1) {
    t.x += __shfl_xor(t.x, o);
    t.y += __shfl_xor(t.y, o);
    t.z += __shfl_xor(t.z, o);
    t.w += __shfl_xor(t.w, o);
  }
  if (lane < 8) {
    int h = lane & 3;
    int ii = (lane < 4) ? i : j;
    int jj = (lane < 4) ? j : i;
    bool ok = (mask[i] != 0) && (mask[j] != 0);
    const float NEG = -3.402823466e38f;
    const float SCALE = (float)(0.08838834764831845 / 19.595917942265423);
    float th = (h == 0) ? t.x : (h == 1) ? t.y : (h == 2) ? t.z : t.w;
    logits[(size_t)h * LL2_ + (size_t)ii * L_ + jj] = ok ? SCALE * th : NEG;
  }
}

// ---------------- K4: row softmax -> attn (bf16) ----------------
__global__ __launch_bounds__(256) void softmax_kernel(
    const float* __restrict__ logits, __bf16* __restrict__ attn) {
  int wave = threadIdx.x >> 6, lane = threadIdx.x & 63;
  int row = blockIdx.x * 4 + wave;  // 0..1535 (= h*384 + i)
  const float* lr = logits + (size_t)row * L_;
  float v[6];
#pragma unroll
  for (int t = 0; t < 6; ++t) v[t] = lr[lane + t * 64];
  float mx = v[0];
#pragma unroll
  for (int t = 1; t < 6; ++t) mx = fmaxf(mx, v[t]);
  mx = wave_max(mx);
  float s = 0.f;
#pragma unroll
  for (int t = 0; t < 6; ++t) { v[t] = __expf(v[t] - mx); s += v[t]; }
  s = wave_sum(s);
  float inv = 1.0f / s;
  __bf16* ar = attn + (size_t)row * L_;
#pragma unroll
  for (int t = 0; t < 6; ++t) ar[lane + t * 64] = f2bf(v[t] * inv);
}

// ------------- K0: transpose W_v, W_out -> bf16 -----------------
__global__ __launch_bounds__(256) void wtrans_kernel(
    const float* __restrict__ Wv, const float* __restrict__ Wo,
    __bf16* __restrict__ WvT, __bf16* __restrict__ WoT) {
  int id = blockIdx.x * 256 + threadIdx.x;  // 0..524287
  int m = id >> 18;
  int e = (id >> 9) & 511, d = id & 511;
  const float* W = m ? Wo : Wv;
  __bf16* T = m ? WoT : WvT;
  T[(size_t)e * 512 + d] = f2bf(W[(size_t)d * 512 + e]);
}

// ---------------- shared machinery ----------------
__device__ __forceinline__ void gload16(const void* g, void* l) {
  __builtin_amdgcn_global_load_lds(
      (const __attribute__((address_space(1))) void*)g,
      (__attribute__((address_space(3))) void*)l, 16, 0, 0);
}

__device__ __forceinline__ unsigned xcd_swz_3072(unsigned bid) {
  return (bid & 7u) * 384u + (bid >> 3);
}
__device__ __forceinline__ unsigned xcd_swz_768(unsigned bid) {
  return (bid & 7u) * 96u + (bid >> 3);
}

// =========== K2 fused: LayerNorm(x) + V^T GEMM ===========
// VT[e][m] = sum_d WvT[e][d] * LN(x)[m][d]
// 128x128 tile, BK=32, 2-slot ping-pong, 37.9 KB LDS -> 4 blocks/CU.
// A (WvT) via global_load_lds (linear dest, pre-swizzled src); B (x)
// reg-staged with LN + bf16 convert (issue-early / write-late).
__global__ __launch_bounds__(256, 4) void gemm_vtln_kernel(
    const __bf16* __restrict__ WvT, const float* __restrict__ x,
    const float* __restrict__ g, const float* __restrict__ b,
    __bf16* __restrict__ VT) {
  __shared__ char lds[37888];
  float* muS = (float*)(lds + 32768);
  float* rsS = (float*)(lds + 33280);
  float* gS  = (float*)(lds + 33792);
  float* bS  = (float*)(lds + 35840);
  unsigned swz = xcd_swz_3072(blockIdx.x + 4 * blockIdx.y);
  int e0 = (swz & 3) * 128;   // WvT tile (group of 4 shares x panel)
  int m0 = (swz >> 2) * 128;  // x panel
  int tid = threadIdx.x, lane = tid & 63, wave = tid >> 6;

  gS[tid] = g[tid]; gS[tid + 256] = g[tid + 256];
  bS[tid] = b[tid]; bS[tid + 256] = b[tid + 256];

  // pass 1: LN stats (wave w -> rows w*32..w*32+31)
  for (int ri = 0; ri < 32; ++ri) {
    int row = wave * 32 + ri;
    const float4* xr = (const float4*)(x + (size_t)(m0 + row) * D_ + lane * 8);
    float4 a0 = xr[0], a1 = xr[1];
    float s1 = a0.x + a0.y + a0.z + a0.w + a1.x + a1.y + a1.z + a1.w;
    float s2 = a0.x * a0.x + a0.y * a0.y + a0.z * a0.z + a0.w * a0.w +
               a1.x * a1.x + a1.y * a1.y + a1.z * a1.z + a1.w * a1.w;
#pragma unroll
    for (int o = 32; o > 0; o >>= 1) {
      s1 += __shfl_xor(s1, o);
      s2 += __shfl_xor(s2, o);
    }
    if (lane == 0) {
      float mu = s1 * (1.0f / D_);
      float var = s2 * (1.0f / D_) - mu * mu;
      muS[row] = mu;
      rsS[row] = rsqrtf(var + 1e-5f);
    }
  }
  __syncthreads();

  int row_u[2], kq_u[2];
#pragma unroll
  for (int u = 0; u < 2; ++u) {
    int cid = u * 256 + tid;
    row_u[u] = cid >> 2;
    kq_u[u] = cid & 3;
  }
  float4 xr0[2], xr1[2];

  auto issue_x = [&](int t) {
#pragma unroll
    for (int u = 0; u < 2; ++u) {
      const float* src = x + (size_t)(m0 + row_u[u]) * D_ + t * 32 + kq_u[u] * 8;
      xr0[u] = *(const float4*)(src);
      xr1[u] = *(const float4*)(src + 4);
    }
  };
  auto gloadA = [&](char* slot, int t) {
#pragma unroll
    for (int it = 0; it < 2; ++it) {
      int cid = it * 256 + tid;
      int row = cid >> 2, c = cid & 3;
      gload16(WvT + (size_t)(e0 + row) * D_ + t * 32 + (c ^ (row & 3)) * 8,
              slot + cid * 16);
    }
  };
  auto ln_write = [&](char* slot, int t) {
#pragma unroll
    for (int u = 0; u < 2; ++u) {
      int row = row_u[u], kq = kq_u[u];
      float mu = muS[row], rs = rsS[row];
      int kc = t * 32 + kq * 8;
      float4 g0 = *(float4*)(gS + kc), g1 = *(float4*)(gS + kc + 4);
      float4 b0 = *(float4*)(bS + kc), b1 = *(float4*)(bS + kc + 4);
      float y[8];
      y[0] = (xr0[u].x - mu) * rs * g0.x + b0.x;
      y[1] = (xr0[u].y - mu) * rs * g0.y + b0.y;
      y[2] = (xr0[u].z - mu) * rs * g0.z + b0.z;
      y[3] = (xr0[u].w - mu) * rs * g0.w + b0.w;
      y[4] = (xr1[u].x - mu) * rs * g1.x + b1.x;
      y[5] = (xr1[u].y - mu) * rs * g1.y + b1.y;
      y[6] = (xr1[u].z - mu) * rs * g1.z + b1.z;
      y[7] = (xr1[u].w - mu) * rs * g1.w + b1.w;
      uint4 pk;
      pk.x = ((unsigned)f2bf_bits(y[1]) << 16) | f2bf_bits(y[0]);
      pk.y = ((unsigned)f2bf_bits(y[3]) << 16) | f2bf_bits(y[2]);
      pk.z = ((unsigned)f2bf_bits(y[5]) << 16) | f2bf_bits(y[4]);
      pk.w = ((unsigned)f2bf_bits(y[7]) << 16) | f2bf_bits(y[6]);
      *(uint4*)(slot + 8192 + row * 64 + ((kq ^ (row & 3)) * 16)) = pk;
    }
  };

  f32x4 acc[4][4] = {};
  int fr = lane & 15;
  int ck = lane >> 4;
  const int NT = D_ / 32;  // 16

  issue_x(0);
  gloadA(lds, 0);
  asm volatile("s_waitcnt vmcnt(0)" ::: "memory");
  ln_write(lds, 0);
  __syncthreads();

  for (int t = 0; t < NT; ++t) {
    char* cur = lds + (t & 1) * 16384;
    char* nxt = lds + ((t + 1) & 1) * 16384;
    if (t + 1 < NT) {
      issue_x(t + 1);
      gloadA(nxt, t + 1);
    }
    bf16x8 af[4], bfv[4];
#pragma unroll
    for (int mi = 0; mi < 4; ++mi) {
      int row = (wave >> 1) * 64 + mi * 16 + fr;
      af[mi] = *(const bf16x8*)(cur + row * 64 + ((ck ^ (row & 3)) * 16));
    }
#pragma unroll
    for (int ni = 0; ni < 4; ++ni) {
      int row = (wave & 1) * 64 + ni * 16 + fr;
      bfv[ni] = *(const bf16x8*)(cur + 8192 + row * 64 + ((ck ^ (row & 3)) * 16));
    }
#pragma unroll
    for (int mi = 0; mi < 4; ++mi)
#pragma unroll
      for (int ni = 0; ni < 4; ++ni)
        acc[mi][ni] = __builtin_amdgcn_mfma_f32_16x16x32_bf16(af[mi], bfv[ni], acc[mi][ni], 0, 0, 0);
    if (t + 1 < NT) {
      asm volatile("s_waitcnt vmcnt(0)" ::: "memory");
      ln_write(nxt, t + 1);
    }
    __syncthreads();
  }

  int cr = (lane >> 4) * 4, cc = lane & 15;
#pragma unroll
  for (int mi = 0; mi < 4; ++mi)
#pragma unroll
    for (int ni = 0; ni < 4; ++ni)
#pragma unroll
      for (int rr = 0; rr < 4; ++rr) {
        int erow = e0 + (wave >> 1) * 64 + mi * 16 + cr + rr;
        int mcol = m0 + (wave & 1) * 64 + ni * 16 + cc;
        VT[(size_t)erow * M1_ + mcol] = f2bf(acc[mi][ni][rr]);
      }
}

// ---------------- R7 GEMM machinery (attnv / gemm_out, unchanged) ----------
template <int NT>
__device__ __forceinline__ void stage_part32(__bf16* s, const __bf16* g, size_t ld) {
  int tid = threadIdx.x;
#pragma unroll
  for (int i = 0; i < 2; ++i) {
    int cid = i * NT + tid;
    int row = cid >> 2, c = cid & 3;
    int cs = c ^ ((row >> 1) & 3);
    gload16(g + (size_t)row * ld + cs * 8, (char*)s + cid * 16);
  }
}

__device__ __forceinline__ bf16x8 frag_ld32(const __bf16* s, int row, int fk) {
  int c = (fk >> 3) ^ ((row >> 1) & 3);
  return *(const bf16x8*)((const char*)s + row * 64 + c * 16);
}

__device__ __forceinline__ void mainloop256(
    const __bf16* __restrict__ A, size_t ldA,
    const __bf16* __restrict__ B, size_t ldB,
    int K, __bf16* lds, f32x4 acc[8][4]) {
  int lane = threadIdx.x & 63, wave = threadIdx.x >> 6;
  int wm = (wave >> 2) * 128, wn = (wave & 3) * 64;
  int fr = lane & 15, fk = (lane >> 4) * 8;
  int nt = K >> 5;
  const int SLOT = 512 * 32;
#pragma unroll
  for (int t = 0; t < 3; ++t) {
    stage_part32<512>(lds + t * SLOT, A + t * 32, ldA);
    stage_part32<512>(lds + t * SLOT + 256 * 32, B + t * 32, ldB);
  }
  for (int t = 0; t < nt; ++t) {
    int rem = nt - 1 - t;
    if (rem >= 2)      asm volatile("s_waitcnt vmcnt(8)" ::: "memory");
    else if (rem == 1) asm volatile("s_waitcnt vmcnt(4)" ::: "memory");
    else               asm volatile("s_waitcnt vmcnt(0)" ::: "memory");
    __builtin_amdgcn_s_barrier();
    const __bf16* As = lds + (t & 3) * SLOT;
    const __bf16* Bs = As + 256 * 32;
    if (t + 3 < nt) {
      __bf16* d = lds + ((t + 3) & 3) * SLOT;
      stage_part32<512>(d, A + (size_t)(t + 3) * 32, ldA);
      stage_part32<512>(d + 256 * 32, B + (size_t)(t + 3) * 32, ldB);
    }
    bf16x8 bfv[4];
#pragma unroll
    for (int ni = 0; ni < 4; ++ni) bfv[ni] = frag_ld32(Bs, wn + ni * 16 + fr, fk);
#pragma unroll
    for (int half = 0; half < 2; ++half) {
      bf16x8 af[4];
#pragma unroll
      for (int mi = 0; mi < 4; ++mi)
        af[mi] = frag_ld32(As, wm + half * 64 + mi * 16 + fr, fk);
      __builtin_amdgcn_s_setprio(1);
#pragma unroll
      for (int mi = 0; mi < 4; ++mi)
#pragma unroll
        for (int ni = 0; ni < 4; ++ni)
          acc[half * 4 + mi][ni] = __builtin_amdgcn_mfma_f32_16x16x32_bf16(
              af[mi], bfv[ni], acc[half * 4 + mi][ni], 0, 0, 0);
      __builtin_amdgcn_s_setprio(0);
    }
  }
}

__device__ __forceinline__ void mainloop128(
    const __bf16* __restrict__ A, size_t ldA,
    const __bf16* __restrict__ B, size_t ldB,
    int K, __bf16* lds, f32x4 acc[4][4]) {
  int lane = threadIdx.x & 63, wave = threadIdx.x >> 6;
  int wm = (wave >> 1) * 64, wn = (wave & 1) * 64;
  int fr = lane & 15, fk = (lane >> 4) * 8;
  int nt = K >> 5;
  const int SLOT = 256 * 32;
#pragma unroll
  for (int t = 0; t < 3; ++t) {
    stage_part32<256>(lds + t * SLOT, A + t * 32, ldA);
    stage_part32<256>(lds + t * SLOT + 128 * 32, B + t * 32, ldB);
  }
  for (int t = 0; t < nt; ++t) {
    int rem = nt - 1 - t;
    if (rem >= 2)      asm volatile("s_waitcnt vmcnt(8)" ::: "memory");
    else if (rem == 1) asm volatile("s_waitcnt vmcnt(4)" ::: "memory");
    else               asm volatile("s_waitcnt vmcnt(0)" ::: "memory");
    __builtin_amdgcn_s_barrier();
    const __bf16* As = lds + (t & 3) * SLOT;
    const __bf16* Bs = As + 128 * 32;
    if (t + 3 < nt) {
      __bf16* d = lds + ((t + 3) & 3) * SLOT;
      stage_part32<256>(d, A + (size_t)(t + 3) * 32, ldA);
      stage_part32<256>(d + 128 * 32, B + (size_t)(t + 3) * 32, ldB);
    }
    bf16x8 bfv[4];
#pragma unroll
    for (int ni = 0; ni < 4; ++ni) bfv[ni] = frag_ld32(Bs, wn + ni * 16 + fr, fk);
#pragma unroll
    for (int half = 0; half < 2; ++half) {
      bf16x8 af[2];
#pragma unroll
      for (int mi = 0; mi < 2; ++mi)
        af[mi] = frag_ld32(As, wm + half * 32 + mi * 16 + fr, fk);
      __builtin_amdgcn_s_setprio(1);
#pragma unroll
      for (int mi = 0; mi < 2; ++mi)
#pragma unroll
        for (int ni = 0; ni < 4; ++ni)
          acc[half * 2 + mi][ni] = __builtin_amdgcn_mfma_f32_16x16x32_bf16(
              af[mi], bfv[ni], acc[half * 2 + mi][ni], 0, 0, 0);
      __builtin_amdgcn_s_setprio(0);
    }
  }
}

// ---- K5: out2[(r,i)][h*128+d] = sum_j attn[h][i][j] * VT[h*128+d][r*384+j] ----
__global__ __launch_bounds__(256) void attnv_kernel(
    const __bf16* __restrict__ attn, const __bf16* __restrict__ VT,
    __bf16* __restrict__ out2) {
  __shared__ __bf16 lds[4 * 256 * 32];
  unsigned swz = xcd_swz_3072(blockIdx.x + 3 * blockIdx.y);
  int it = swz % 3u;
  int rh = swz / 3u;
  int h = rh & 3, r = rh >> 2;
  const __bf16* A = attn + (size_t)h * LL2_ + (size_t)it * 128 * L_;
  const __bf16* Bt = VT + (size_t)(h * 128) * M1_ + (size_t)r * L_;
  f32x4 acc[4][4] = {};
  mainloop128(A, L_, Bt, M1_, L_, lds, acc);
  int lane = threadIdx.x & 63, wave = threadIdx.x >> 6;
  int wm = (wave >> 1) * 64, wn = (wave & 1) * 64;
  int cr = (lane >> 4) * 4, cc = lane & 15;
#pragma unroll
  for (int mi = 0; mi < 4; ++mi)
#pragma unroll
    for (int ni = 0; ni < 4; ++ni)
#pragma unroll
      for (int rr = 0; rr < 4; ++rr) {
        int row_i = it * 128 + wm + mi * 16 + cr + rr;
        int col = h * 128 + wn + ni * 16 + cc;
        out2[((size_t)r * L_ + row_i) * D_ + col] = f2bf(acc[mi][ni][rr]);
      }
}

// ---- K6: out[m][f] = x[m][f] + sum_e out2[m][e] * WoT[f][e], 256^2 tile ----
__global__ __launch_bounds__(512, 1) void gemm_out_kernel(
    const __bf16* __restrict__ out2, const __bf16* __restrict__ WoT,
    const float* __restrict__ x, float* __restrict__ out) {
  __shared__ __bf16 lds[4 * 512 * 32];
  unsigned swz = xcd_swz_768(blockIdx.x + 2 * blockIdx.y);
  int n0 = (swz & 1) * 256;
  int m0 = (swz >> 1) * 256;
  f32x4 acc[8][4] = {};
  mainloop256(out2 + (size_t)m0 * D_, D_, WoT + (size_t)n0 * D_, D_, D_, lds, acc);
  int lane = threadIdx.x & 63, wave = threadIdx.x >> 6;
  int wm = (wave >> 2) * 128, wn = (wave & 3) * 64;
  int cr = (lane >> 4) * 4, cc = lane & 15;
#pragma unroll
  for (int mi = 0; mi < 8; ++mi)
#pragma unroll
    for (int ni = 0; ni < 4; ++ni)
#pragma unroll
      for (int rr = 0; rr < 4; ++rr) {
        int row = m0 + wm + mi * 16 + cr + rr;
        int col = n0 + wn + ni * 16 + cc;
        size_t idx = (size_t)row * D_ + col;
        out[idx] = x[idx] + acc[mi][ni][rr];
      }
}

extern "C" void kernel_launch(void* const* d_in, const int* in_sizes, int n_in,
                              void* d_out, int out_size, void* d_ws, size_t ws_size,
                              hipStream_t stream) {
  const float* x      = (const float*)d_in[0];
  const float* pair   = (const float*)d_in[1];
  const int*   mask   = (const int*)d_in[2];
  const float* g_msa  = (const float*)d_in[3];
  const float* b_msa  = (const float*)d_in[4];
  const float* g_pair = (const float*)d_in[5];
  const float* b_pair = (const float*)d_in[6];
  const float* Wp     = (const float*)d_in[7];
  const float* Wv     = (const float*)d_in[8];
  const float* Wo     = (const float*)d_in[9];
  float* out = (float*)d_out;

  char* p = (char*)d_ws;
  auto alloc = [&](size_t bytes) {
    char* r = p;
    p += (bytes + 255) & ~(size_t)255;
    return r;
  };
  __bf16* VT     = (__bf16*)alloc((size_t)D_ * M1_ * 2);  // 100.7 MB
  __bf16* out2   = (__bf16*)alloc((size_t)M1_ * D_ * 2);  // 100.7 MB
  float*  logits = (float*)alloc((size_t)H_ * LL2_ * 4);  // 2.36 MB
  __bf16* attn   = (__bf16*)alloc((size_t)H_ * LL2_ * 2); // 1.18 MB
  __bf16* WvT    = (__bf16*)alloc((size_t)512 * 512 * 2);
  __bf16* WoT    = (__bf16*)alloc((size_t)512 * 512 * 2);

  wtrans_kernel<<<2048, 256, 0, stream>>>(Wv, Wo, WvT, WoT);
  gemm_vtln_kernel<<<dim3(4, M1_ / 128), 256, 0, stream>>>(WvT, x, g_msa, b_msa, VT);
  pair_logits_kernel<<<NPAIR_BLOCKS, 256, 0, stream>>>(pair, mask, g_pair, b_pair, Wp, logits);
  softmax_kernel<<<(H_ * L_) / 4, 256, 0, stream>>>(logits, attn);
  attnv_kernel<<<dim3(3, RR_ * H_), 256, 0, stream>>>(attn, VT, out2);
  gemm_out_kernel<<<dim3(2, M1_ / 256), 512, 0, stream>>>(out2, WoT, x, out);
}

// Round 9
// 448.517 us; speedup vs baseline: 1.0227x; 1.0227x over previous
//
#include <hip/hip_runtime.h>

// dims
#define L_   384
#define D_   512
#define C_   256
#define H_   4
#define RR_  256
#define M1_  98304   // R*L
#define LL2_ 147456  // L*L
#define NPAIR_BLOCKS 18480  // 73920 pairs / 4 waves per block

typedef __bf16 bf16x8 __attribute__((ext_vector_type(8)));
typedef float f32x4 __attribute__((ext_vector_type(4)));

__device__ __forceinline__ unsigned short f2bf_bits(float f) {
  union { float f; unsigned u; } v; v.f = f;
  return (unsigned short)((v.u + 0x7fffu + ((v.u >> 16) & 1u)) >> 16);
}
__device__ __forceinline__ __bf16 f2bf(float f) {
  union { unsigned short s; __bf16 b; } o; o.s = f2bf_bits(f);
  return o.b;
}

__device__ __forceinline__ float wave_sum(float v) {
#pragma unroll
  for (int o = 32; o > 0; o >>= 1) v += __shfl_xor(v, o);
  return v;
}
__device__ __forceinline__ float wave_max(float v) {
#pragma unroll
  for (int o = 32; o > 0; o >>= 1) v = fmaxf(v, __shfl_xor(v, o));
  return v;
}

// ------ K3: pair symmetrize + LN + per-head logits (+mask) ------
__global__ __launch_bounds__(256) void pair_logits_kernel(
    const float* __restrict__ pf, const int* __restrict__ mask,
    const float* __restrict__ g, const float* __restrict__ b,
    const float* __restrict__ Wp, float* __restrict__ logits) {
  unsigned wid = blockIdx.x * 4 + (threadIdx.x >> 6);  // 0..73919
  int lane = threadIdx.x & 63;
  unsigned a = wid / 385u;
  unsigned c = wid - a * 385u;
  int i, j;
  if (c < 384u - a) { i = a; j = a + c; }
  else { i = 383 - a; j = i + (c - (384 - a)); }

  int c0 = lane * 4;
  float4 p1 = *(const float4*)(pf + ((size_t)i * L_ + j) * C_ + c0);
  float4 p2 = *(const float4*)(pf + ((size_t)j * L_ + i) * C_ + c0);
  float4 v;
  v.x = 0.5f * (p1.x + p2.x); v.y = 0.5f * (p1.y + p2.y);
  v.z = 0.5f * (p1.z + p2.z); v.w = 0.5f * (p1.w + p2.w);
  float s1 = v.x + v.y + v.z + v.w;
  float s2 = v.x * v.x + v.y * v.y + v.z * v.z + v.w * v.w;
#pragma unroll
  for (int o = 32; o > 0; o >>= 1) {
    s1 += __shfl_xor(s1, o);
    s2 += __shfl_xor(s2, o);
  }
  float mu = s1 * (1.0f / C_);
  float var = s2 * (1.0f / C_) - mu * mu;
  float rs = rsqrtf(var + 1e-5f);
  float4 gv = *(const float4*)(g + c0);
  float4 bv = *(const float4*)(b + c0);
  float y0 = (v.x - mu) * rs * gv.x + bv.x;
  float y1 = (v.y - mu) * rs * gv.y + bv.y;
  float y2 = (v.z - mu) * rs * gv.z + bv.z;
  float y3 = (v.w - mu) * rs * gv.w + bv.w;
  const float4* wp = (const float4*)Wp;  // [256][4]
  float4 w0 = wp[c0], w1 = wp[c0 + 1], w2 = wp[c0 + 2], w3 = wp[c0 + 3];
  float4 t;
  t.x = y0 * w0.x + y1 * w1.x + y2 * w2.x + y3 * w3.x;
  t.y = y0 * w0.y + y1 * w1.y + y2 * w2.y + y3 * w3.y;
  t.z = y0 * w0.z + y1 * w1.z + y2 * w2.z + y3 * w3.z;
  t.w = y0 * w0.w + y1 * w1.w + y2 * w2.w + y3 * w3.w;
#pragma unroll
  for (int o = 32; o > 0; o >>= 1) {
    t.x += __shfl_xor(t.x, o);
    t.y += __shfl_xor(t.y, o);
    t.z += __shfl_xor(t.z, o);
    t.w += __shfl_xor(t.w, o);
  }
  if (lane < 8) {
    int h = lane & 3;
    int ii = (lane < 4) ? i : j;
    int jj = (lane < 4) ? j : i;
    bool ok = (mask[i] != 0) && (mask[j] != 0);
    const float NEG = -3.402823466e38f;
    const float SCALE = (float)(0.08838834764831845 / 19.595917942265423);
    float th = (h == 0) ? t.x : (h == 1) ? t.y : (h == 2) ? t.z : t.w;
    logits[(size_t)h * LL2_ + (size_t)ii * L_ + jj] = ok ? SCALE * th : NEG;
  }
}

// ---------------- K4: row softmax -> attn (bf16) ----------------
__global__ __launch_bounds__(256) void softmax_kernel(
    const float* __restrict__ logits, __bf16* __restrict__ attn) {
  int wave = threadIdx.x >> 6, lane = threadIdx.x & 63;
  int row = blockIdx.x * 4 + wave;  // 0..1535 (= h*384 + i)
  const float* lr = logits + (size_t)row * L_;
  float v[6];
#pragma unroll
  for (int t = 0; t < 6; ++t) v[t] = lr[lane + t * 64];
  float mx = v[0];
#pragma unroll
  for (int t = 1; t < 6; ++t) mx = fmaxf(mx, v[t]);
  mx = wave_max(mx);
  float s = 0.f;
#pragma unroll
  for (int t = 0; t < 6; ++t) { v[t] = __expf(v[t] - mx); s += v[t]; }
  s = wave_sum(s);
  float inv = 1.0f / s;
  __bf16* ar = attn + (size_t)row * L_;
#pragma unroll
  for (int t = 0; t < 6; ++t) ar[lane + t * 64] = f2bf(v[t] * inv);
}

// ------------- K0: transpose W_v, W_out -> bf16 -----------------
__global__ __launch_bounds__(256) void wtrans_kernel(
    const float* __restrict__ Wv, const float* __restrict__ Wo,
    __bf16* __restrict__ WvT, __bf16* __restrict__ WoT) {
  int id = blockIdx.x * 256 + threadIdx.x;  // 0..524287
  int m = id >> 18;
  int e = (id >> 9) & 511, d = id & 511;
  const float* W = m ? Wo : Wv;
  __bf16* T = m ? WoT : WvT;
  T[(size_t)e * 512 + d] = f2bf(W[(size_t)d * 512 + e]);
}

// ---------------- shared machinery ----------------
__device__ __forceinline__ void gload16(const void* g, void* l) {
  __builtin_amdgcn_global_load_lds(
      (const __attribute__((address_space(1))) void*)g,
      (__attribute__((address_space(3))) void*)l, 16, 0, 0);
}

__device__ __forceinline__ unsigned xcd_swz_3072(unsigned bid) {
  return (bid & 7u) * 384u + (bid >> 3);
}
__device__ __forceinline__ unsigned xcd_swz_768(unsigned bid) {
  return (bid & 7u) * 96u + (bid >> 3);
}

// LDS row of 64B = 4 chunks of 16B; conflict-free swizzle uses (row>>1)&3
// (row&1 is already consumed by the 128B bank period).
__device__ __forceinline__ bf16x8 frag_ld32(const __bf16* s, int row, int fk) {
  int c = (fk >> 3) ^ ((row >> 1) & 3);
  return *(const bf16x8*)((const char*)s + row * 64 + c * 16);
}

// =========== K2 fused: LayerNorm(x) + V^T GEMM (v2) ===========
// VT[e][m] = sum_d WvT[e][d] * LN(x)[m][d]
// 128x128 tile, BK=32, 2-slot ping-pong, 37.9 KB LDS -> 4 blocks/CU.
// A (WvT) via global_load_lds; B (x) reg-staged + LN + bf16, ds_write.
// Issue order per tile: x-loads FIRST, then A-gloads (FIFO: compiler's
// register wait for x retires only x, leaving A in flight). One barrier
// per tile, preceded by own vmcnt(0)+lgkmcnt(0).
__global__ __launch_bounds__(256, 4) void gemm_vtln_kernel(
    const __bf16* __restrict__ WvT, const float* __restrict__ x,
    const float* __restrict__ g, const float* __restrict__ b,
    __bf16* __restrict__ VT) {
  __shared__ char lds[37888];
  float* muS = (float*)(lds + 32768);
  float* rsS = (float*)(lds + 33280);
  float* gS  = (float*)(lds + 33792);
  float* bS  = (float*)(lds + 35840);
  unsigned swz = xcd_swz_3072(blockIdx.x + 4 * blockIdx.y);
  int e0 = (swz & 3) * 128;   // WvT tile (group of 4 shares x panel)
  int m0 = (swz >> 2) * 128;  // x panel
  int tid = threadIdx.x, lane = tid & 63, wave = tid >> 6;

  gS[tid] = g[tid]; gS[tid + 256] = g[tid + 256];
  bS[tid] = b[tid]; bS[tid + 256] = b[tid + 256];

  // pass 1: LN stats (wave w -> rows w*32..w*32+31)
  for (int ri = 0; ri < 32; ++ri) {
    int row = wave * 32 + ri;
    const float4* xr = (const float4*)(x + (size_t)(m0 + row) * D_ + lane * 8);
    float4 a0 = xr[0], a1 = xr[1];
    float s1 = a0.x + a0.y + a0.z + a0.w + a1.x + a1.y + a1.z + a1.w;
    float s2 = a0.x * a0.x + a0.y * a0.y + a0.z * a0.z + a0.w * a0.w +
               a1.x * a1.x + a1.y * a1.y + a1.z * a1.z + a1.w * a1.w;
#pragma unroll
    for (int o = 32; o > 0; o >>= 1) {
      s1 += __shfl_xor(s1, o);
      s2 += __shfl_xor(s2, o);
    }
    if (lane == 0) {
      float mu = s1 * (1.0f / D_);
      float var = s2 * (1.0f / D_) - mu * mu;
      muS[row] = mu;
      rsS[row] = rsqrtf(var + 1e-5f);
    }
  }
  __syncthreads();

  int row_u[2], kq_u[2];
#pragma unroll
  for (int u = 0; u < 2; ++u) {
    int cid = u * 256 + tid;
    row_u[u] = cid >> 2;
    kq_u[u] = cid & 3;
  }
  float4 xr0[2], xr1[2];

  auto issue_x = [&](int t) {
#pragma unroll
    for (int u = 0; u < 2; ++u) {
      const float* src = x + (size_t)(m0 + row_u[u]) * D_ + t * 32 + kq_u[u] * 8;
      xr0[u] = *(const float4*)(src);
      xr1[u] = *(const float4*)(src + 4);
    }
  };
  auto gloadA = [&](char* slot, int t) {
#pragma unroll
    for (int it = 0; it < 2; ++it) {
      int cid = it * 256 + tid;
      int row = cid >> 2, c = cid & 3;
      gload16(WvT + (size_t)(e0 + row) * D_ + t * 32 + (c ^ ((row >> 1) & 3)) * 8,
              slot + cid * 16);
    }
  };
  auto ln_write = [&](char* slot, int t) {
#pragma unroll
    for (int u = 0; u < 2; ++u) {
      int row = row_u[u], kq = kq_u[u];
      float mu = muS[row], rs = rsS[row];
      int kc = t * 32 + kq * 8;
      float4 g0 = *(float4*)(gS + kc), g1 = *(float4*)(gS + kc + 4);
      float4 b0 = *(float4*)(bS + kc), b1 = *(float4*)(bS + kc + 4);
      float y[8];
      y[0] = (xr0[u].x - mu) * rs * g0.x + b0.x;
      y[1] = (xr0[u].y - mu) * rs * g0.y + b0.y;
      y[2] = (xr0[u].z - mu) * rs * g0.z + b0.z;
      y[3] = (xr0[u].w - mu) * rs * g0.w + b0.w;
      y[4] = (xr1[u].x - mu) * rs * g1.x + b1.x;
      y[5] = (xr1[u].y - mu) * rs * g1.y + b1.y;
      y[6] = (xr1[u].z - mu) * rs * g1.z + b1.z;
      y[7] = (xr1[u].w - mu) * rs * g1.w + b1.w;
      uint4 pk;
      pk.x = ((unsigned)f2bf_bits(y[1]) << 16) | f2bf_bits(y[0]);
      pk.y = ((unsigned)f2bf_bits(y[3]) << 16) | f2bf_bits(y[2]);
      pk.z = ((unsigned)f2bf_bits(y[5]) << 16) | f2bf_bits(y[4]);
      pk.w = ((unsigned)f2bf_bits(y[7]) << 16) | f2bf_bits(y[6]);
      *(uint4*)(slot + 8192 + row * 64 + ((kq ^ ((row >> 1) & 3)) * 16)) = pk;
    }
  };

  f32x4 acc[4][4] = {};
  int fr = lane & 15;
  int fk = (lane >> 4) * 8;
  const int NT = D_ / 32;  // 16

  // prologue: tile 0 (x first, then A — FIFO discipline)
  issue_x(0);
  __builtin_amdgcn_sched_barrier(0);
  gloadA(lds, 0);
  ln_write(lds, 0);  // compiler inserts the minimal vmcnt for xr regs

  for (int t = 0; t < NT; ++t) {
    asm volatile("s_waitcnt vmcnt(0) lgkmcnt(0)" ::: "memory");
    __builtin_amdgcn_s_barrier();
    __builtin_amdgcn_sched_barrier(0);
    char* cur = lds + (t & 1) * 16384;
    char* nxt = lds + ((t + 1) & 1) * 16384;
    if (t + 1 < NT) {
      issue_x(t + 1);
      __builtin_amdgcn_sched_barrier(0);
      gloadA(nxt, t + 1);
    }
    bf16x8 af[4], bfv[4];
#pragma unroll
    for (int mi = 0; mi < 4; ++mi) {
      int row = (wave >> 1) * 64 + mi * 16 + fr;
      af[mi] = frag_ld32((const __bf16*)cur, row, fk);
    }
#pragma unroll
    for (int ni = 0; ni < 4; ++ni) {
      int row = (wave & 1) * 64 + ni * 16 + fr;
      bfv[ni] = frag_ld32((const __bf16*)(cur + 8192), row, fk);
    }
    __builtin_amdgcn_s_setprio(1);
#pragma unroll
    for (int mi = 0; mi < 4; ++mi)
#pragma unroll
      for (int ni = 0; ni < 4; ++ni)
        acc[mi][ni] = __builtin_amdgcn_mfma_f32_16x16x32_bf16(af[mi], bfv[ni], acc[mi][ni], 0, 0, 0);
    __builtin_amdgcn_s_setprio(0);
    if (t + 1 < NT) ln_write(nxt, t + 1);
  }

  int cr = (lane >> 4) * 4, cc = lane & 15;
#pragma unroll
  for (int mi = 0; mi < 4; ++mi)
#pragma unroll
    for (int ni = 0; ni < 4; ++ni)
#pragma unroll
      for (int rr = 0; rr < 4; ++rr) {
        int erow = e0 + (wave >> 1) * 64 + mi * 16 + cr + rr;
        int mcol = m0 + (wave & 1) * 64 + ni * 16 + cc;
        VT[(size_t)erow * M1_ + mcol] = f2bf(acc[mi][ni][rr]);
      }
}

// ---------------- R7 GEMM machinery (attnv / gemm_out, unchanged) ----------
template <int NT>
__device__ __forceinline__ void stage_part32(__bf16* s, const __bf16* g, size_t ld) {
  int tid = threadIdx.x;
#pragma unroll
  for (int i = 0; i < 2; ++i) {
    int cid = i * NT + tid;
    int row = cid >> 2, c = cid & 3;
    int cs = c ^ ((row >> 1) & 3);
    gload16(g + (size_t)row * ld + cs * 8, (char*)s + cid * 16);
  }
}

__device__ __forceinline__ void mainloop256(
    const __bf16* __restrict__ A, size_t ldA,
    const __bf16* __restrict__ B, size_t ldB,
    int K, __bf16* lds, f32x4 acc[8][4]) {
  int lane = threadIdx.x & 63, wave = threadIdx.x >> 6;
  int wm = (wave >> 2) * 128, wn = (wave & 3) * 64;
  int fr = lane & 15, fk = (lane >> 4) * 8;
  int nt = K >> 5;
  const int SLOT = 512 * 32;
#pragma unroll
  for (int t = 0; t < 3; ++t) {
    stage_part32<512>(lds + t * SLOT, A + t * 32, ldA);
    stage_part32<512>(lds + t * SLOT + 256 * 32, B + t * 32, ldB);
  }
  for (int t = 0; t < nt; ++t) {
    int rem = nt - 1 - t;
    if (rem >= 2)      asm volatile("s_waitcnt vmcnt(8)" ::: "memory");
    else if (rem == 1) asm volatile("s_waitcnt vmcnt(4)" ::: "memory");
    else               asm volatile("s_waitcnt vmcnt(0)" ::: "memory");
    __builtin_amdgcn_s_barrier();
    const __bf16* As = lds + (t & 3) * SLOT;
    const __bf16* Bs = As + 256 * 32;
    if (t + 3 < nt) {
      __bf16* d = lds + ((t + 3) & 3) * SLOT;
      stage_part32<512>(d, A + (size_t)(t + 3) * 32, ldA);
      stage_part32<512>(d + 256 * 32, B + (size_t)(t + 3) * 32, ldB);
    }
    bf16x8 bfv[4];
#pragma unroll
    for (int ni = 0; ni < 4; ++ni) bfv[ni] = frag_ld32(Bs, wn + ni * 16 + fr, fk);
#pragma unroll
    for (int half = 0; half < 2; ++half) {
      bf16x8 af[4];
#pragma unroll
      for (int mi = 0; mi < 4; ++mi)
        af[mi] = frag_ld32(As, wm + half * 64 + mi * 16 + fr, fk);
      __builtin_amdgcn_s_setprio(1);
#pragma unroll
      for (int mi = 0; mi < 4; ++mi)
#pragma unroll
        for (int ni = 0; ni < 4; ++ni)
          acc[half * 4 + mi][ni] = __builtin_amdgcn_mfma_f32_16x16x32_bf16(
              af[mi], bfv[ni], acc[half * 4 + mi][ni], 0, 0, 0);
      __builtin_amdgcn_s_setprio(0);
    }
  }
}

__device__ __forceinline__ void mainloop128(
    const __bf16* __restrict__ A, size_t ldA,
    const __bf16* __restrict__ B, size_t ldB,
    int K, __bf16* lds, f32x4 acc[4][4]) {
  int lane = threadIdx.x & 63, wave = threadIdx.x >> 6;
  int wm = (wave >> 1) * 64, wn = (wave & 1) * 64;
  int fr = lane & 15, fk = (lane >> 4) * 8;
  int nt = K >> 5;
  const int SLOT = 256 * 32;
#pragma unroll
  for (int t = 0; t < 3; ++t) {
    stage_part32<256>(lds + t * SLOT, A + t * 32, ldA);
    stage_part32<256>(lds + t * SLOT + 128 * 32, B + t * 32, ldB);
  }
  for (int t = 0; t < nt; ++t) {
    int rem = nt - 1 - t;
    if (rem >= 2)      asm volatile("s_waitcnt vmcnt(8)" ::: "memory");
    else if (rem == 1) asm volatile("s_waitcnt vmcnt(4)" ::: "memory");
    else               asm volatile("s_waitcnt vmcnt(0)" ::: "memory");
    __builtin_amdgcn_s_barrier();
    const __bf16* As = lds + (t & 3) * SLOT;
    const __bf16* Bs = As + 128 * 32;
    if (t + 3 < nt) {
      __bf16* d = lds + ((t + 3) & 3) * SLOT;
      stage_part32<256>(d, A + (size_t)(t + 3) * 32, ldA);
      stage_part32<256>(d + 128 * 32, B + (size_t)(t + 3) * 32, ldB);
    }
    bf16x8 bfv[4];
#pragma unroll
    for (int ni = 0; ni < 4; ++ni) bfv[ni] = frag_ld32(Bs, wn + ni * 16 + fr, fk);
#pragma unroll
    for (int half = 0; half < 2; ++half) {
      bf16x8 af[2];
#pragma unroll
      for (int mi = 0; mi < 2; ++mi)
        af[mi] = frag_ld32(As, wm + half * 32 + mi * 16 + fr, fk);
      __builtin_amdgcn_s_setprio(1);
#pragma unroll
      for (int mi = 0; mi < 2; ++mi)
#pragma unroll
        for (int ni = 0; ni < 4; ++ni)
          acc[half * 2 + mi][ni] = __builtin_amdgcn_mfma_f32_16x16x32_bf16(
              af[mi], bfv[ni], acc[half * 2 + mi][ni], 0, 0, 0);
      __builtin_amdgcn_s_setprio(0);
    }
  }
}

// ---- K5: out2[(r,i)][h*128+d] = sum_j attn[h][i][j] * VT[h*128+d][r*384+j] ----
__global__ __launch_bounds__(256) void attnv_kernel(
    const __bf16* __restrict__ attn, const __bf16* __restrict__ VT,
    __bf16* __restrict__ out2) {
  __shared__ __bf16 lds[4 * 256 * 32];
  unsigned swz = xcd_swz_3072(blockIdx.x + 3 * blockIdx.y);
  int it = swz % 3u;
  int rh = swz / 3u;
  int h = rh & 3, r = rh >> 2;
  const __bf16* A = attn + (size_t)h * LL2_ + (size_t)it * 128 * L_;
  const __bf16* Bt = VT + (size_t)(h * 128) * M1_ + (size_t)r * L_;
  f32x4 acc[4][4] = {};
  mainloop128(A, L_, Bt, M1_, L_, lds, acc);
  int lane = threadIdx.x & 63, wave = threadIdx.x >> 6;
  int wm = (wave >> 1) * 64, wn = (wave & 1) * 64;
  int cr = (lane >> 4) * 4, cc = lane & 15;
#pragma unroll
  for (int mi = 0; mi < 4; ++mi)
#pragma unroll
    for (int ni = 0; ni < 4; ++ni)
#pragma unroll
      for (int rr = 0; rr < 4; ++rr) {
        int row_i = it * 128 + wm + mi * 16 + cr + rr;
        int col = h * 128 + wn + ni * 16 + cc;
        out2[((size_t)r * L_ + row_i) * D_ + col] = f2bf(acc[mi][ni][rr]);
      }
}

// ---- K6: out[m][f] = x[m][f] + sum_e out2[m][e] * WoT[f][e], 256^2 tile ----
__global__ __launch_bounds__(512, 1) void gemm_out_kernel(
    const __bf16* __restrict__ out2, const __bf16* __restrict__ WoT,
    const float* __restrict__ x, float* __restrict__ out) {
  __shared__ __bf16 lds[4 * 512 * 32];
  unsigned swz = xcd_swz_768(blockIdx.x + 2 * blockIdx.y);
  int n0 = (swz & 1) * 256;
  int m0 = (swz >> 1) * 256;
  f32x4 acc[8][4] = {};
  mainloop256(out2 + (size_t)m0 * D_, D_, WoT + (size_t)n0 * D_, D_, D_, lds, acc);
  int lane = threadIdx.x & 63, wave = threadIdx.x >> 6;
  int wm = (wave >> 2) * 128, wn = (wave & 3) * 64;
  int cr = (lane >> 4) * 4, cc = lane & 15;
#pragma unroll
  for (int mi = 0; mi < 8; ++mi)
#pragma unroll
    for (int ni = 0; ni < 4; ++ni)
#pragma unroll
      for (int rr = 0; rr < 4; ++rr) {
        int row = m0 + wm + mi * 16 + cr + rr;
        int col = n0 + wn + ni * 16 + cc;
        size_t idx = (size_t)row * D_ + col;
        out[idx] = x[idx] + acc[mi][ni][rr];
      }
}

extern "C" void kernel_launch(void* const* d_in, const int* in_sizes, int n_in,
                              void* d_out, int out_size, void* d_ws, size_t ws_size,
                              hipStream_t stream) {
  const float* x      = (const float*)d_in[0];
  const float* pair   = (const float*)d_in[1];
  const int*   mask   = (const int*)d_in[2];
  const float* g_msa  = (const float*)d_in[3];
  const float* b_msa  = (const float*)d_in[4];
  const float* g_pair = (const float*)d_in[5];
  const float* b_pair = (const float*)d_in[6];
  const float* Wp     = (const float*)d_in[7];
  const float* Wv     = (const float*)d_in[8];
  const float* Wo     = (const float*)d_in[9];
  float* out = (float*)d_out;

  char* p = (char*)d_ws;
  auto alloc = [&](size_t bytes) {
    char* r = p;
    p += (bytes + 255) & ~(size_t)255;
    return r;
  };
  __bf16* VT     = (__bf16*)alloc((size_t)D_ * M1_ * 2);  // 100.7 MB
  __bf16* out2   = (__bf16*)alloc((size_t)M1_ * D_ * 2);  // 100.7 MB
  float*  logits = (float*)alloc((size_t)H_ * LL2_ * 4);  // 2.36 MB
  __bf16* attn   = (__bf16*)alloc((size_t)H_ * LL2_ * 2); // 1.18 MB
  __bf16* WvT    = (__bf16*)alloc((size_t)512 * 512 * 2);
  __bf16* WoT    = (__bf16*)alloc((size_t)512 * 512 * 2);

  wtrans_kernel<<<2048, 256, 0, stream>>>(Wv, Wo, WvT, WoT);
  gemm_vtln_kernel<<<dim3(4, M1_ / 128), 256, 0, stream>>>(WvT, x, g_msa, b_msa, VT);
  pair_logits_kernel<<<NPAIR_BLOCKS, 256, 0, stream>>>(pair, mask, g_pair, b_pair, Wp, logits);
  softmax_kernel<<<(H_ * L_) / 4, 256, 0, stream>>>(logits, attn);
  attnv_kernel<<<dim3(3, RR_ * H_), 256, 0, stream>>>(attn, VT, out2);
  gemm_out_kernel<<<dim3(2, M1_ / 256), 512, 0, stream>>>(out2, WoT, x, out);
}

// Round 10
// 375.893 us; speedup vs baseline: 1.2203x; 1.1932x over previous
//
#include <hip/hip_runtime.h>

// dims
#define L_   384
#define D_   512
#define C_   256
#define H_   4
#define RR_  256
#define M1_  98304   // R*L
#define LL2_ 147456  // L*L
#define NPAIR_BLOCKS 18480  // 73920 pairs / 4 waves per block

typedef __bf16 bf16x8 __attribute__((ext_vector_type(8)));
typedef float f32x4 __attribute__((ext_vector_type(4)));

__device__ __forceinline__ unsigned short f2bf_bits(float f) {
  union { float f; unsigned u; } v; v.f = f;
  return (unsigned short)((v.u + 0x7fffu + ((v.u >> 16) & 1u)) >> 16);
}
__device__ __forceinline__ __bf16 f2bf(float f) {
  union { unsigned short s; __bf16 b; } o; o.s = f2bf_bits(f);
  return o.b;
}

// ---------------- K1: LayerNorm(x) -> msa (bf16), wave-per-row ----------------
__global__ __launch_bounds__(256) void ln_msa_kernel(
    const float* __restrict__ x, const float* __restrict__ g,
    const float* __restrict__ b, __bf16* __restrict__ msa) {
  int row = blockIdx.x * 4 + (threadIdx.x >> 6);
  int lane = threadIdx.x & 63;
  const float4* xr = (const float4*)(x + (size_t)row * D_ + lane * 8);
  float4 v0 = xr[0], v1 = xr[1];
  float s1 = v0.x + v0.y + v0.z + v0.w + v1.x + v1.y + v1.z + v1.w;
  float s2 = v0.x * v0.x + v0.y * v0.y + v0.z * v0.z + v0.w * v0.w +
             v1.x * v1.x + v1.y * v1.y + v1.z * v1.z + v1.w * v1.w;
#pragma unroll
  for (int o = 32; o > 0; o >>= 1) {
    s1 += __shfl_xor(s1, o);
    s2 += __shfl_xor(s2, o);
  }
  float mu = s1 * (1.0f / D_);
  float var = s2 * (1.0f / D_) - mu * mu;
  float rs = rsqrtf(var + 1e-5f);
  const float4* gp = (const float4*)(g + lane * 8);
  const float4* bp = (const float4*)(b + lane * 8);
  float4 g0 = gp[0], g1 = gp[1], b0 = bp[0], b1 = bp[1];
  float y[8];
  y[0] = (v0.x - mu) * rs * g0.x + b0.x;
  y[1] = (v0.y - mu) * rs * g0.y + b0.y;
  y[2] = (v0.z - mu) * rs * g0.z + b0.z;
  y[3] = (v0.w - mu) * rs * g0.w + b0.w;
  y[4] = (v1.x - mu) * rs * g1.x + b1.x;
  y[5] = (v1.y - mu) * rs * g1.y + b1.y;
  y[6] = (v1.z - mu) * rs * g1.z + b1.z;
  y[7] = (v1.w - mu) * rs * g1.w + b1.w;
  uint4 pk;
  pk.x = ((unsigned)f2bf_bits(y[1]) << 16) | f2bf_bits(y[0]);
  pk.y = ((unsigned)f2bf_bits(y[3]) << 16) | f2bf_bits(y[2]);
  pk.z = ((unsigned)f2bf_bits(y[5]) << 16) | f2bf_bits(y[4]);
  pk.w = ((unsigned)f2bf_bits(y[7]) << 16) | f2bf_bits(y[6]);
  *(uint4*)(msa + (size_t)row * D_ + lane * 8) = pk;
}

// ------ K3: pair symmetrize + LN + per-head logits (+mask) ------
__global__ __launch_bounds__(256) void pair_logits_kernel(
    const float* __restrict__ pf, const int* __restrict__ mask,
    const float* __restrict__ g, const float* __restrict__ b,
    const float* __restrict__ Wp, float* __restrict__ logits) {
  unsigned wid = blockIdx.x * 4 + (threadIdx.x >> 6);  // 0..73919
  int lane = threadIdx.x & 63;
  unsigned a = wid / 385u;
  unsigned c = wid - a * 385u;
  int i, j;
  if (c < 384u - a) { i = a; j = a + c; }
  else { i = 383 - a; j = i + (c - (384 - a)); }

  int c0 = lane * 4;
  float4 p1 = *(const float4*)(pf + ((size_t)i * L_ + j) * C_ + c0);
  float4 p2 = *(const float4*)(pf + ((size_t)j * L_ + i) * C_ + c0);
  float4 v;
  v.x = 0.5f * (p1.x + p2.x); v.y = 0.5f * (p1.y + p2.y);
  v.z = 0.5f * (p1.z + p2.z); v.w = 0.5f * (p1.w + p2.w);
  float s1 = v.x + v.y + v.z + v.w;
  float s2 = v.x * v.x + v.y * v.y + v.z * v.z + v.w * v.w;
#pragma unroll
  for (int o = 32; o > 0; o >>= 1) {
    s1 += __shfl_xor(s1, o);
    s2 += __shfl_xor(s2, o);
  }
  float mu = s1 * (1.0f / C_);
  float var = s2 * (1.0f / C_) - mu * mu;
  float rs = rsqrtf(var + 1e-5f);
  float4 gv = *(const float4*)(g + c0);
  float4 bv = *(const float4*)(b + c0);
  float y0 = (v.x - mu) * rs * gv.x + bv.x;
  float y1 = (v.y - mu) * rs * gv.y + bv.y;
  float y2 = (v.z - mu) * rs * gv.z + bv.z;
  float y3 = (v.w - mu) * rs * gv.w + bv.w;
  const float4* wp = (const float4*)Wp;  // [256][4]
  float4 w0 = wp[c0], w1 = wp[c0 + 1], w2 = wp[c0 + 2], w3 = wp[c0 + 3];
  float4 t;
  t.x = y0 * w0.x + y1 * w1.x + y2 * w2.x + y3 * w3.x;
  t.y = y0 * w0.y + y1 * w1.y + y2 * w2.y + y3 * w3.y;
  t.z = y0 * w0.z + y1 * w1.z + y2 * w2.z + y3 * w3.z;
  t.w = y0 * w0.w + y1 * w1.w + y2 * w2.w + y3 * w3.w;
#pragma unroll
  for (int o = 32; o > 0; o >>= 1) {
    t.x += __shfl_xor(t.x, o);
    t.y += __shfl_xor(t.y, o);
    t.z += __shfl_xor(t.z, o);
    t.w += __shfl_xor(t.w, o);
  }
  if (lane < 8) {
    int h = lane & 3;
    int ii = (lane < 4) ? i : j;
    int jj = (lane < 4) ? j : i;
    bool ok = (mask[i] != 0) && (mask[j] != 0);
    const float NEG = -3.402823466e38f;
    const float SCALE = (float)(0.08838834764831845 / 19.595917942265423);
    float th = (h == 0) ? t.x : (h == 1) ? t.y : (h == 2) ? t.z : t.w;
    logits[(size_t)h * LL2_ + (size_t)ii * L_ + jj] = ok ? SCALE * th : NEG;
  }
}

// ---------------- K4: row softmax -> attn (bf16) ----------------
__global__ __launch_bounds__(256) void softmax_kernel(
    const float* __restrict__ logits, __bf16* __restrict__ attn) {
  int wave = threadIdx.x >> 6, lane = threadIdx.x & 63;
  int row = blockIdx.x * 4 + wave;  // 0..1535 (= h*384 + i)
  const float* lr = logits + (size_t)row * L_;
  float v[6];
#pragma unroll
  for (int t = 0; t < 6; ++t) v[t] = lr[lane + t * 64];
  float mx = v[0];
#pragma unroll
  for (int t = 1; t < 6; ++t) mx = fmaxf(mx, v[t]);
#pragma unroll
  for (int o = 32; o > 0; o >>= 1) mx = fmaxf(mx, __shfl_xor(mx, o));
  float s = 0.f;
#pragma unroll
  for (int t = 0; t < 6; ++t) { v[t] = __expf(v[t] - mx); s += v[t]; }
#pragma unroll
  for (int o = 32; o > 0; o >>= 1) s += __shfl_xor(s, o);
  float inv = 1.0f / s;
  __bf16* ar = attn + (size_t)row * L_;
#pragma unroll
  for (int t = 0; t < 6; ++t) ar[lane + t * 64] = f2bf(v[t] * inv);
}

// ------------- K0: transpose W_v, W_out -> bf16 -----------------
__global__ __launch_bounds__(256) void wtrans_kernel(
    const float* __restrict__ Wv, const float* __restrict__ Wo,
    __bf16* __restrict__ WvT, __bf16* __restrict__ WoT) {
  int id = blockIdx.x * 256 + threadIdx.x;  // 0..524287
  int m = id >> 18;
  int e = (id >> 9) & 511, d = id & 511;
  const float* W = m ? Wo : Wv;
  __bf16* T = m ? WoT : WvT;
  T[(size_t)e * 512 + d] = f2bf(W[(size_t)d * 512 + e]);
}

// ---------------- shared GEMM machinery (BK=32) ----------------
__device__ __forceinline__ void gload16(const void* g, void* l) {
  __builtin_amdgcn_global_load_lds(
      (const __attribute__((address_space(1))) void*)g,
      (__attribute__((address_space(3))) void*)l, 16, 0, 0);
}

__device__ __forceinline__ unsigned xcd_swz_3072(unsigned bid) {
  return (bid & 7u) * 384u + (bid >> 3);
}
__device__ __forceinline__ unsigned xcd_swz_768(unsigned bid) {
  return (bid & 7u) * 96u + (bid >> 3);
}

// LDS row of 64B = 4 chunks of 16B; conflict-free swizzle uses (row>>1)&3.
template <int NT>
__device__ __forceinline__ void stage_part32(__bf16* s, const __bf16* g, size_t ld) {
  int tid = threadIdx.x;
#pragma unroll
  for (int i = 0; i < 2; ++i) {
    int cid = i * NT + tid;
    int row = cid >> 2, c = cid & 3;
    int cs = c ^ ((row >> 1) & 3);
    gload16(g + (size_t)row * ld + cs * 8, (char*)s + cid * 16);
  }
}

__device__ __forceinline__ bf16x8 frag_ld32(const __bf16* s, int row, int fk) {
  int c = (fk >> 3) ^ ((row >> 1) & 3);
  return *(const bf16x8*)((const char*)s + row * 64 + c * 16);
}

// ---- 256x256 tile, 512 thr, 8 waves, BK=32, 2-slot ping-pong (64 KB) ----
// 4 loads/thread/tile. Per iter: issue stage(t+1) -> vmcnt(4) retires tile t
// (FIFO) -> barrier -> ds_read + MFMA. 64 KB LDS => 2 blocks/CU so one
// block's epilogue overlaps the other's mainloop.
__device__ __forceinline__ void mainloop256_2s(
    const __bf16* __restrict__ A, size_t ldA,
    const __bf16* __restrict__ B, size_t ldB,
    int K, __bf16* lds, f32x4 acc[8][4]) {
  int lane = threadIdx.x & 63, wave = threadIdx.x >> 6;
  int wm = (wave >> 2) * 128, wn = (wave & 3) * 64;
  int fr = lane & 15, fk = (lane >> 4) * 8;
  int nt = K >> 5;
  const int SLOT = 512 * 32;  // A 256x32 + B 256x32 elems
  stage_part32<512>(lds, A, ldA);
  stage_part32<512>(lds + 256 * 32, B, ldB);
  for (int t = 0; t < nt; ++t) {
    const __bf16* As = lds + (t & 1) * SLOT;
    const __bf16* Bs = As + 256 * 32;
    if (t + 1 < nt) {
      __bf16* d = lds + ((t + 1) & 1) * SLOT;
      stage_part32<512>(d, A + (size_t)(t + 1) * 32, ldA);
      stage_part32<512>(d + 256 * 32, B + (size_t)(t + 1) * 32, ldB);
      asm volatile("s_waitcnt vmcnt(4)" ::: "memory");
    } else {
      asm volatile("s_waitcnt vmcnt(0)" ::: "memory");
    }
    __builtin_amdgcn_s_barrier();
    bf16x8 bfv[4];
#pragma unroll
    for (int ni = 0; ni < 4; ++ni) bfv[ni] = frag_ld32(Bs, wn + ni * 16 + fr, fk);
#pragma unroll
    for (int half = 0; half < 2; ++half) {
      bf16x8 af[4];
#pragma unroll
      for (int mi = 0; mi < 4; ++mi)
        af[mi] = frag_ld32(As, wm + half * 64 + mi * 16 + fr, fk);
      __builtin_amdgcn_s_setprio(1);
#pragma unroll
      for (int mi = 0; mi < 4; ++mi)
#pragma unroll
        for (int ni = 0; ni < 4; ++ni)
          acc[half * 4 + mi][ni] = __builtin_amdgcn_mfma_f32_16x16x32_bf16(
              af[mi], bfv[ni], acc[half * 4 + mi][ni], 0, 0, 0);
      __builtin_amdgcn_s_setprio(0);
    }
  }
}

// ---- 128x128 tile, 256 thr, 4 waves, BK=32, 4-slot ring (64 KB) ----
__device__ __forceinline__ void mainloop128(
    const __bf16* __restrict__ A, size_t ldA,
    const __bf16* __restrict__ B, size_t ldB,
    int K, __bf16* lds, f32x4 acc[4][4]) {
  int lane = threadIdx.x & 63, wave = threadIdx.x >> 6;
  int wm = (wave >> 1) * 64, wn = (wave & 1) * 64;
  int fr = lane & 15, fk = (lane >> 4) * 8;
  int nt = K >> 5;
  const int SLOT = 256 * 32;
#pragma unroll
  for (int t = 0; t < 3; ++t) {
    stage_part32<256>(lds + t * SLOT, A + t * 32, ldA);
    stage_part32<256>(lds + t * SLOT + 128 * 32, B + t * 32, ldB);
  }
  for (int t = 0; t < nt; ++t) {
    int rem = nt - 1 - t;
    if (rem >= 2)      asm volatile("s_waitcnt vmcnt(8)" ::: "memory");
    else if (rem == 1) asm volatile("s_waitcnt vmcnt(4)" ::: "memory");
    else               asm volatile("s_waitcnt vmcnt(0)" ::: "memory");
    __builtin_amdgcn_s_barrier();
    const __bf16* As = lds + (t & 3) * SLOT;
    const __bf16* Bs = As + 128 * 32;
    if (t + 3 < nt) {
      __bf16* d = lds + ((t + 3) & 3) * SLOT;
      stage_part32<256>(d, A + (size_t)(t + 3) * 32, ldA);
      stage_part32<256>(d + 128 * 32, B + (size_t)(t + 3) * 32, ldB);
    }
    bf16x8 bfv[4];
#pragma unroll
    for (int ni = 0; ni < 4; ++ni) bfv[ni] = frag_ld32(Bs, wn + ni * 16 + fr, fk);
#pragma unroll
    for (int half = 0; half < 2; ++half) {
      bf16x8 af[2];
#pragma unroll
      for (int mi = 0; mi < 2; ++mi)
        af[mi] = frag_ld32(As, wm + half * 32 + mi * 16 + fr, fk);
      __builtin_amdgcn_s_setprio(1);
#pragma unroll
      for (int mi = 0; mi < 2; ++mi)
#pragma unroll
        for (int ni = 0; ni < 4; ++ni)
          acc[half * 2 + mi][ni] = __builtin_amdgcn_mfma_f32_16x16x32_bf16(
              af[mi], bfv[ni], acc[half * 2 + mi][ni], 0, 0, 0);
      __builtin_amdgcn_s_setprio(0);
    }
  }
}

// ---- K2: VT[e][m] = sum_d WvT[e][d] * msa[m][d], 256^2 / 2-slot ----
__global__ __launch_bounds__(512) void gemm_vt_kernel(
    const __bf16* __restrict__ WvT, const __bf16* __restrict__ msa,
    __bf16* __restrict__ VT) {
  __shared__ __bf16 lds[2 * 512 * 32];  // 64 KB
  unsigned swz = xcd_swz_768(blockIdx.x + 2 * blockIdx.y);
  int m0 = (swz & 1) * 256;        // e-tile
  int n0 = (swz >> 1) * 256;       // msa panel
  f32x4 acc[8][4] = {};
  mainloop256_2s(WvT + (size_t)m0 * D_, D_, msa + (size_t)n0 * D_, D_, D_, lds, acc);
  int lane = threadIdx.x & 63, wave = threadIdx.x >> 6;
  int wm = (wave >> 2) * 128, wn = (wave & 3) * 64;
  int cr = (lane >> 4) * 4, cc = lane & 15;
#pragma unroll
  for (int mi = 0; mi < 8; ++mi)
#pragma unroll
    for (int ni = 0; ni < 4; ++ni)
#pragma unroll
      for (int rr = 0; rr < 4; ++rr) {
        int row = m0 + wm + mi * 16 + cr + rr;
        int col = n0 + wn + ni * 16 + cc;
        VT[(size_t)row * M1_ + col] = f2bf(acc[mi][ni][rr]);
      }
}

// ---- K5: out2[(r,i)][h*128+d] = sum_j attn[h][i][j] * VT[h*128+d][r*384+j] ----
__global__ __launch_bounds__(256) void attnv_kernel(
    const __bf16* __restrict__ attn, const __bf16* __restrict__ VT,
    __bf16* __restrict__ out2) {
  __shared__ __bf16 lds[4 * 256 * 32];  // 64 KB
  unsigned swz = xcd_swz_3072(blockIdx.x + 3 * blockIdx.y);
  int it = swz % 3u;
  int rh = swz / 3u;
  int h = rh & 3, r = rh >> 2;
  const __bf16* A = attn + (size_t)h * LL2_ + (size_t)it * 128 * L_;
  const __bf16* Bt = VT + (size_t)(h * 128) * M1_ + (size_t)r * L_;
  f32x4 acc[4][4] = {};
  mainloop128(A, L_, Bt, M1_, L_, lds, acc);
  int lane = threadIdx.x & 63, wave = threadIdx.x >> 6;
  int wm = (wave >> 1) * 64, wn = (wave & 1) * 64;
  int cr = (lane >> 4) * 4, cc = lane & 15;
#pragma unroll
  for (int mi = 0; mi < 4; ++mi)
#pragma unroll
    for (int ni = 0; ni < 4; ++ni)
#pragma unroll
      for (int rr = 0; rr < 4; ++rr) {
        int row_i = it * 128 + wm + mi * 16 + cr + rr;
        int col = h * 128 + wn + ni * 16 + cc;
        out2[((size_t)r * L_ + row_i) * D_ + col] = f2bf(acc[mi][ni][rr]);
      }
}

// ---- K6: out[m][f] = x[m][f] + sum_e out2[m][e] * WoT[f][e], 256^2 / 2-slot ----
__global__ __launch_bounds__(512) void gemm_out_kernel(
    const __bf16* __restrict__ out2, const __bf16* __restrict__ WoT,
    const float* __restrict__ x, float* __restrict__ out) {
  __shared__ __bf16 lds[2 * 512 * 32];  // 64 KB
  unsigned swz = xcd_swz_768(blockIdx.x + 2 * blockIdx.y);
  int n0 = (swz & 1) * 256;
  int m0 = (swz >> 1) * 256;
  f32x4 acc[8][4] = {};
  mainloop256_2s(out2 + (size_t)m0 * D_, D_, WoT + (size_t)n0 * D_, D_, D_, lds, acc);
  int lane = threadIdx.x & 63, wave = threadIdx.x >> 6;
  int wm = (wave >> 2) * 128, wn = (wave & 3) * 64;
  int cr = (lane >> 4) * 4, cc = lane & 15;
#pragma unroll
  for (int mi = 0; mi < 8; ++mi)
#pragma unroll
    for (int ni = 0; ni < 4; ++ni)
#pragma unroll
      for (int rr = 0; rr < 4; ++rr) {
        int row = m0 + wm + mi * 16 + cr + rr;
        int col = n0 + wn + ni * 16 + cc;
        size_t idx = (size_t)row * D_ + col;
        out[idx] = x[idx] + acc[mi][ni][rr];
      }
}

extern "C" void kernel_launch(void* const* d_in, const int* in_sizes, int n_in,
                              void* d_out, int out_size, void* d_ws, size_t ws_size,
                              hipStream_t stream) {
  const float* x      = (const float*)d_in[0];
  const float* pair   = (const float*)d_in[1];
  const int*   mask   = (const int*)d_in[2];
  const float* g_msa  = (const float*)d_in[3];
  const float* b_msa  = (const float*)d_in[4];
  const float* g_pair = (const float*)d_in[5];
  const float* b_pair = (const float*)d_in[6];
  const float* Wp     = (const float*)d_in[7];
  const float* Wv     = (const float*)d_in[8];
  const float* Wo     = (const float*)d_in[9];
  float* out = (float*)d_out;

  char* p = (char*)d_ws;
  auto alloc = [&](size_t bytes) {
    char* r = p;
    p += (bytes + 255) & ~(size_t)255;
    return r;
  };
  __bf16* msa    = (__bf16*)alloc((size_t)M1_ * D_ * 2);  // 100.7 MB (reused as out2)
  __bf16* VT     = (__bf16*)alloc((size_t)D_ * M1_ * 2);  // 100.7 MB
  float*  logits = (float*)alloc((size_t)H_ * LL2_ * 4);  // 2.36 MB
  __bf16* attn   = (__bf16*)alloc((size_t)H_ * LL2_ * 2); // 1.18 MB
  __bf16* WvT    = (__bf16*)alloc((size_t)512 * 512 * 2);
  __bf16* WoT    = (__bf16*)alloc((size_t)512 * 512 * 2);
  __bf16* out2   = msa;  // msa dead after gemm_vt_kernel

  wtrans_kernel<<<2048, 256, 0, stream>>>(Wv, Wo, WvT, WoT);
  ln_msa_kernel<<<M1_ / 4, 256, 0, stream>>>(x, g_msa, b_msa, msa);
  gemm_vt_kernel<<<dim3(2, M1_ / 256), 512, 0, stream>>>(WvT, msa, VT);
  pair_logits_kernel<<<NPAIR_BLOCKS, 256, 0, stream>>>(pair, mask, g_pair, b_pair, Wp, logits);
  softmax_kernel<<<(H_ * L_) / 4, 256, 0, stream>>>(logits, attn);
  attnv_kernel<<<dim3(3, RR_ * H_), 256, 0, stream>>>(attn, VT, out2);
  gemm_out_kernel<<<dim3(2, M1_ / 256), 512, 0, stream>>>(out2, WoT, x, out);
}